// Round 14
// baseline (188.407 us; speedup 1.0000x reference)
//
#include <hip/hip_runtime.h>
#include <hip/hip_bf16.h>

typedef __hip_bfloat16 bf16;
typedef _Float16 f16;
typedef __attribute__((ext_vector_type(8))) short bf16x8;
typedef __attribute__((ext_vector_type(8))) _Float16 f16x8;
typedef __attribute__((ext_vector_type(2))) _Float16 f16x2;
typedef __attribute__((ext_vector_type(4))) float f32x4;
typedef __attribute__((ext_vector_type(4))) unsigned int u32x4;
typedef __attribute__((ext_vector_type(2))) unsigned int u32x2;

#define B_ 4
#define N_ 4096
#define C_ 256
#define H_ 4
#define D_ 64
#define KLN 0.18033688011112042f   /* 0.125 * log2(e): folded into Q */

#if __has_builtin(__builtin_amdgcn_exp2f)
#define EXP2(x) __builtin_amdgcn_exp2f(x)
#else
#define EXP2(x) exp2f(x)
#endif
#if __has_builtin(__builtin_amdgcn_rcpf)
#define RCP(x) __builtin_amdgcn_rcpf(x)
#else
#define RCP(x) (1.0f / (x))
#endif

// direct global->LDS DMA, 16B per lane. LDS dest = wave-uniform base + lane*16.
__device__ inline void load_lds16(const void* g, void* l) {
#if __has_builtin(__builtin_amdgcn_global_load_lds)
    __builtin_amdgcn_global_load_lds(
        (const __attribute__((address_space(1))) unsigned int*)g,
        (__attribute__((address_space(3))) unsigned int*)l, 16, 0, 0);
#else
    int ln = __lane_id();
    ((u32x4*)l)[ln] = *((const u32x4*)g);   // fallback (not used on gfx950)
#endif
}

// two fp32 -> packed bf16 pair (round-half-up)
__device__ inline unsigned int pk2(float a, float b) {
    unsigned int ua = __builtin_bit_cast(unsigned int, a) + 0x8000u;
    unsigned int ub = __builtin_bit_cast(unsigned int, b) + 0x8000u;
    return (ua >> 16) | (ub & 0xffff0000u);
}
// two fp32 -> packed f16 pair (single v_cvt_pkrtz_f16_f32)
__device__ inline unsigned int pkh2(float a, float b) {
#if __has_builtin(__builtin_amdgcn_cvt_pkrtz)
    return __builtin_bit_cast(unsigned int, __builtin_amdgcn_cvt_pkrtz(a, b));
#else
    f16x2 h = { (f16)a, (f16)b };
    return __builtin_bit_cast(unsigned int, h);
#endif
}

// ---------------------------------------------------------------------------
// Prep: cast x, w_qkv, w_proj fp32 -> bf16 (memory-bound).
// ---------------------------------------------------------------------------
__global__ __launch_bounds__(256) void cast_bf16(const float* __restrict__ x,
                                                 const float* __restrict__ wq,
                                                 const float* __restrict__ wp,
                                                 bf16* __restrict__ xb,
                                                 bf16* __restrict__ wqb,
                                                 bf16* __restrict__ wpb)
{
    int bid = blockIdx.x;
    const float* s; bf16* d; int base;
    if (bid < 2048)      { s = x;  d = xb;  base = bid * 2048; }
    else if (bid < 2144) { s = wq; d = wqb; base = (bid - 2048) * 2048; }
    else                 { s = wp; d = wpb; base = (bid - 2144) * 2048; }
    int i = base + threadIdx.x * 8;
    f32x4 a = *reinterpret_cast<const f32x4*>(s + i);
    f32x4 b = *reinterpret_cast<const f32x4*>(s + i + 4);
    u32x4 o;
    o.x = pk2(a[0], a[1]); o.y = pk2(a[2], a[3]);
    o.z = pk2(b[0], b[1]); o.w = pk2(b[2], b[3]);
    *reinterpret_cast<u32x4*>(d + i) = o;
}

// ---------------------------------------------------------------------------
// QKV projection — round-3 version (best measured non-attn config).
// ---------------------------------------------------------------------------
__global__ __launch_bounds__(256, 2) void qkv_fast(const bf16* __restrict__ x,
                                                   const bf16* __restrict__ w,
                                                   bf16* __restrict__ qw,
                                                   bf16* __restrict__ kw,
                                                   f16* __restrict__ vtw)
{
    __shared__ short w_s[64][264];
    const int tid  = threadIdx.x;
    const int lane = tid & 63;
    const int wav  = tid >> 6;
    const int quad = lane >> 4;
    const int l16  = lane & 15;
    const int bid = (blockIdx.x & 7) * 192 + (blockIdx.x >> 3);   // 1536 = 8*192
    const int mt = bid / 12, nb = bid % 12;
    const int m0 = mt * 128, n0 = nb * 64;

    {
        const int row = tid >> 2, cb = (tid & 3) * 64;
        const bf16* src = w + (size_t)(n0 + row) * C_ + cb;
#pragma unroll
        for (int i = 0; i < 8; ++i)
            *reinterpret_cast<bf16x8*>(&w_s[row][cb + i * 8]) =
                *reinterpret_cast<const bf16x8*>(src + i * 8);
    }
    __syncthreads();

#pragma unroll
    for (int half = 0; half < 2; ++half) {
        const int mh = m0 + half * 64;
        f32x4 acc[4] = {{0,0,0,0},{0,0,0,0},{0,0,0,0},{0,0,0,0}};
        const bf16* xrow = x + (size_t)(mh + wav * 16 + l16) * C_ + quad * 8;
        if (nb < 8) {        // Q/K: transposed accumulator (swapped operands)
#pragma unroll
            for (int k0 = 0; k0 < C_; k0 += 32) {
                bf16x8 a = *reinterpret_cast<const bf16x8*>(xrow + k0);
#pragma unroll
                for (int nt = 0; nt < 4; ++nt) {
                    bf16x8 b = *reinterpret_cast<const bf16x8*>(&w_s[nt * 16 + l16][k0 + quad * 8]);
                    acc[nt] = __builtin_amdgcn_mfma_f32_16x16x32_bf16(b, a, acc[nt], 0, 0, 0);
                }
            }
        } else {             // V: normal orientation (store wants n-contiguous)
#pragma unroll
            for (int k0 = 0; k0 < C_; k0 += 32) {
                bf16x8 a = *reinterpret_cast<const bf16x8*>(xrow + k0);
#pragma unroll
                for (int nt = 0; nt < 4; ++nt) {
                    bf16x8 b = *reinterpret_cast<const bf16x8*>(&w_s[nt * 16 + l16][k0 + quad * 8]);
                    acc[nt] = __builtin_amdgcn_mfma_f32_16x16x32_bf16(a, b, acc[nt], 0, 0, 0);
                }
            }
        }

        const int bb = mh >> 12;
        const int nbase = (mh + wav * 16) & (N_ - 1);
        if (nb < 4) {                            // Q (scaled): row n = nbase+l16
            bf16* dst = qw + (((size_t)bb * H_ + nb) * N_ + nbase + l16) * D_;
#pragma unroll
            for (int nt = 0; nt < 4; ++nt) {
                u32x2 wv = { pk2(acc[nt][0] * KLN, acc[nt][1] * KLN),
                             pk2(acc[nt][2] * KLN, acc[nt][3] * KLN) };
                *reinterpret_cast<u32x2*>(dst + nt * 16 + quad * 4) = wv;
            }
        } else if (nb < 8) {                     // K
            bf16* dst = kw + (((size_t)bb * H_ + (nb - 4)) * N_ + nbase + l16) * D_;
#pragma unroll
            for (int nt = 0; nt < 4; ++nt) {
                u32x2 wv = { pk2(acc[nt][0], acc[nt][1]),
                             pk2(acc[nt][2], acc[nt][3]) };
                *reinterpret_cast<u32x2*>(dst + nt * 16 + quad * 4) = wv;
            }
        } else {                                 // V transposed, f16
            const int h = nb - 8;
#pragma unroll
            for (int nt = 0; nt < 4; ++nt) {
                int d = nt * 16 + l16;
                u32x2 wv;
                wv.x = pkh2(acc[nt][0], acc[nt][1]);
                wv.y = pkh2(acc[nt][2], acc[nt][3]);
                *reinterpret_cast<u32x2*>(
                    vtw + (((size_t)bb * H_ + h) * D_ + d) * N_ + nbase + quad * 4) = wv;
            }
        }
    }
}

// ---------------------------------------------------------------------------
// Flash attention v16 (resubmit; r13 run died to container infra).
// v15's pipeline at DOUBLE independent occupancy. Cross-round matrix:
// r1 = 4 waves/SIMD barrier-locked -> 72.1us; v15 = 2 waves/SIMD
// independent -> 73.6us (clean, no spill, MfmaUtil 45 + VALU 40, ~11us of
// neither-pipe bubbles). Untested cell: 4 waves/SIMD ALL INDEPENDENT.
// v16: 64-row q-tiles, grid 1024 = 4 blocks/CU (VGPR < 128, LDS 40KB x 4
// = 160KB exactly). Each block = 4 waves = 1 wave/SIMD -> every wave on a
// SIMD is from a DIFFERENT block: maximally independent streams, so one
// wave's exp/VALU phase can fill another's MFMA drain and the barrier
// bubbles. Per-wave work halves (1 q-group); per-CU totals unchanged; K/V
// re-reads (2x) are L2-resident (~17 of 34.5 TB/s). Same 6-periodic
// schedule, math and j-order identical to v15 -> same absmax.
// ---------------------------------------------------------------------------
__global__ __launch_bounds__(256, 4) void attn(const bf16* __restrict__ q,
                                               const bf16* __restrict__ k,
                                               const f16* __restrict__ vt,
                                               bf16* __restrict__ o)
{
    __shared__ __align__(16) char smem[40960];
    short* k_s = reinterpret_cast<short*>(smem);            // [2][4096] bf16
    f16*   v_s = reinterpret_cast<f16*>(smem + 16384);      // [3][4096] f16

    const int tid  = threadIdx.x;
    const int lane = tid & 63;
    const int wav  = tid >> 6;       // 0..3: q-sub (16 rows each)
    const int quad = lane >> 4;
    const int l16  = lane & 15;
    const int l8   = lane & 7;

    const int wg = (blockIdx.x & 7) * 128 + (blockIdx.x >> 3);  // XCD swizzle
    const int bh = wg >> 6;          // 64 q-tiles per (b,h)
    const int qt = wg & 63;
    const int bb = bh >> 2, h = bh & 3;

    const bf16* qp = q  + (size_t)bh * N_ * D_;
    const bf16* kp = k  + (size_t)bh * N_ * D_;
    const f16*  vp = vt + (size_t)bh * D_ * N_;

    const int qbase = qt * 64 + wav * 16;
    bf16x8 qb0, qb1;
    qb0 = *reinterpret_cast<const bf16x8*>(
        qp + (size_t)(qbase + l16) * D_ + quad * 8);
    qb1 = *reinterpret_cast<const bf16x8*>(
        qp + (size_t)(qbase + l16) * D_ + 32 + quad * 8);

    // staging geometry: lane -> (row ri, stored slot ci); logical chunk = ci^ri
    const int ri = lane >> 3;
    const int ci = lane & 7;
    const int gc = ci ^ ri;
    int koff[2], voff[2], lds_r[2];
#pragma unroll
    for (int g = 0; g < 2; ++g) {
        const int rb  = wav * 16 + g * 8;     // this wave stages 16 rows of 64
        const int rho = rb + ri;
        const int pr  = (rho & 32) | ((rho & 12) << 1) | ((rho & 16) >> 2) | (rho & 3);
        koff[g]  = pr * D_ + gc * 8;          // K: permuted row, swizzled chunk
        voff[g]  = rho * N_ + gc * 8;         // V: linear d-row, swizzled chunk
        lds_r[g] = rb * 64;
    }

    f32x4 oacc[4];
    f32x4 lacc = (f32x4){0, 0, 0, 0};
#pragma unroll
    for (int dt = 0; dt < 4; ++dt) oacc[dt] = (f32x4){0, 0, 0, 0};
    const f16x8 onesA = {1.f16, 1.f16, 1.f16, 1.f16, 1.f16, 1.f16, 1.f16, 1.f16};

    f32x4 s[4];                     // this tile's S^T (QK output, pre-exp)
    f16x8 pbE[2], pbO[2];           // P fragments: even / odd tiles

// stage tile t into K buf kbuf, V slot vslot
#define STAGE(kbuf, vslot, t) do {                                            \
    const int j0_ = (t) * 64;                                                 \
    short* kd_ = k_s + (kbuf) * 4096;                                         \
    f16*   vd_ = v_s + (vslot) * 4096;                                        \
    load_lds16(kp + (size_t)j0_ * D_ + koff[0], kd_ + lds_r[0]);              \
    load_lds16(kp + (size_t)j0_ * D_ + koff[1], kd_ + lds_r[1]);              \
    load_lds16(vp + j0_ + voff[0],              vd_ + lds_r[0]);              \
    load_lds16(vp + j0_ + voff[1],              vd_ + lds_r[1]);              \
} while (0)

// QK(t): S^T = K.Q^T from K buffer kbuf (per-nt K fragments: 8-reg transient)
#define QK(kbuf) do {                                                         \
    const short* kt_ = k_s + (kbuf) * 4096;                                   \
    _Pragma("unroll")                                                         \
    for (int nt = 0; nt < 4; ++nt) {                                          \
        const int rb_ = (nt * 16 + l16) * 64;                                 \
        bf16x8 ka0_ = *reinterpret_cast<const bf16x8*>(kt_ + rb_ + ((quad    ) ^ l8) * 8); \
        bf16x8 ka1_ = *reinterpret_cast<const bf16x8*>(kt_ + rb_ + ((4 + quad) ^ l8) * 8); \
        s[nt] = __builtin_amdgcn_mfma_f32_16x16x32_bf16(                      \
            ka0_, qb0, (f32x4){0.f, 0.f, 0.f, 0.f}, 0, 0, 0);                 \
        s[nt] = __builtin_amdgcn_mfma_f32_16x16x32_bf16(                      \
            ka1_, qb1, s[nt], 0, 0, 0);                                       \
    }                                                                         \
} while (0)

// PV(t-1) + l(t-1): consumes PB (named array, compile-time indices)
#define PV(vslot, PB) do {                                                    \
    const f16* vt_ = v_s + (vslot) * 4096;                                    \
    lacc = __builtin_amdgcn_mfma_f32_16x16x32_f16(onesA, PB[0], lacc, 0, 0, 0); \
    lacc = __builtin_amdgcn_mfma_f32_16x16x32_f16(onesA, PB[1], lacc, 0, 0, 0); \
    _Pragma("unroll")                                                         \
    for (int ks = 0; ks < 2; ++ks) {                                          \
        _Pragma("unroll")                                                     \
        for (int dt = 0; dt < 4; ++dt) {                                      \
            f16x8 va_ = *reinterpret_cast<const f16x8*>(                      \
                vt_ + (dt * 16 + l16) * 64 + (((ks << 2) + quad) ^ l8) * 8);  \
            oacc[dt] = __builtin_amdgcn_mfma_f32_16x16x32_f16(va_, PB[ks], oacc[dt], 0, 0, 0); \
        }                                                                     \
    }                                                                         \
} while (0)

// exp(t): p = exp2(s) -> PB (VALU; overlaps other waves' MFMA drains)
#define EXPP(PB) do {                                                         \
    _Pragma("unroll")                                                         \
    for (int ks = 0; ks < 2; ++ks) {                                          \
        const f32x4 sa_ = s[2 * ks], sb_ = s[2 * ks + 1];                     \
        u32x4 pw_;                                                            \
        pw_.x = pkh2(EXP2(sa_[0]), EXP2(sa_[1]));                             \
        pw_.y = pkh2(EXP2(sa_[2]), EXP2(sa_[3]));                             \
        pw_.z = pkh2(EXP2(sb_[0]), EXP2(sb_[1]));                             \
        pw_.w = pkh2(EXP2(sb_[2]), EXP2(sb_[3]));                             \
        PB[ks] = __builtin_bit_cast(f16x8, pw_);                              \
    }                                                                         \
} while (0)

#define SB __builtin_amdgcn_sched_barrier(0)

    // ---- pipeline: tile t = {stage t+1 | PV(t-1) | QK(t) | exp(t)} ----
    STAGE(0, 0, 0);
    __syncthreads();

    // t = 0 (no PV yet)
    STAGE(1, 1, 1);
    QK(0); EXPP(pbE);
    __syncthreads();

    // t = 1
    STAGE(0, 2, 2);
    PV(0, pbE); SB; QK(1); EXPP(pbO);
    __syncthreads();

#pragma unroll 1
    for (int tb = 2; tb <= 56; tb += 6) {
        // t = tb+0  (t%6==2)
        STAGE(1, 0, tb + 1);
        PV(1, pbO); SB; QK(0); EXPP(pbE);
        __syncthreads();
        // t = tb+1  (t%6==3)
        STAGE(0, 1, tb + 2);
        PV(2, pbE); SB; QK(1); EXPP(pbO);
        __syncthreads();
        // t = tb+2  (t%6==4)
        STAGE(1, 2, tb + 3);
        PV(0, pbO); SB; QK(0); EXPP(pbE);
        __syncthreads();
        // t = tb+3  (t%6==5)
        STAGE(0, 0, tb + 4);
        PV(1, pbE); SB; QK(1); EXPP(pbO);
        __syncthreads();
        // t = tb+4  (t%6==0)
        STAGE(1, 1, tb + 5);
        PV(2, pbO); SB; QK(0); EXPP(pbE);
        __syncthreads();
        // t = tb+5  (t%6==1)
        STAGE(0, 2, tb + 6);
        PV(0, pbE); SB; QK(1); EXPP(pbO);
        __syncthreads();
    }
    // tail: t = 62 (t%6==2)
    STAGE(1, 0, 63);
    PV(1, pbO); SB; QK(0); EXPP(pbE);
    __syncthreads();
    // tail: t = 63 (t%6==3), no stage
    PV(2, pbE); SB; QK(1); EXPP(pbO);
    // epilogue: PV + l for t = 63 (V(63) in slot 0, odd tile -> pbO)
    PV(0, pbO);

    // ---- normalize + store ----
    {
        const float rl = RCP(lacc[0]);
        const size_t obase = ((size_t)bb * N_ + qbase + l16) * C_ + h * D_;
#pragma unroll
        for (int dt = 0; dt < 4; ++dt) {
            float v0 = oacc[dt][0] * rl;
            float v1 = oacc[dt][1] * rl;
            float v2 = oacc[dt][2] * rl;
            float v3 = oacc[dt][3] * rl;
            u32x2 wv = { pk2(v0, v1), pk2(v2, v3) };
            *reinterpret_cast<u32x2*>(o + obase + dt * 16 + quad * 4) = wv;
        }
    }
}

// ---------------------------------------------------------------------------
// Output projection — round-3 version.
// ---------------------------------------------------------------------------
__global__ __launch_bounds__(256, 2) void out_proj_fast(const bf16* __restrict__ ov,
                                                        const bf16* __restrict__ w,
                                                        const float* __restrict__ bias,
                                                        float* __restrict__ out)
{
    __shared__ short w_s[64][264];
    const int tid  = threadIdx.x;
    const int lane = tid & 63;
    const int wav  = tid >> 6;
    const int quad = lane >> 4;
    const int l16  = lane & 15;
    const int bid = (blockIdx.x & 7) * 64 + (blockIdx.x >> 3);   // 512 = 8*64
    const int m0 = (bid >> 2) * 128;
    const int n0 = (bid & 3) * 64;

    {
        const int row = tid >> 2, cb = (tid & 3) * 64;
        const bf16* src = w + (size_t)(n0 + row) * C_ + cb;
#pragma unroll
        for (int i = 0; i < 8; ++i)
            *reinterpret_cast<bf16x8*>(&w_s[row][cb + i * 8]) =
                *reinterpret_cast<const bf16x8*>(src + i * 8);
    }
    __syncthreads();

#pragma unroll
    for (int half = 0; half < 2; ++half) {
        const int mh = m0 + half * 64;
        f32x4 acc[4] = {{0,0,0,0},{0,0,0,0},{0,0,0,0},{0,0,0,0}};
        const bf16* orow = ov + (size_t)(mh + wav * 16 + l16) * C_ + quad * 8;
#pragma unroll
        for (int k0 = 0; k0 < C_; k0 += 32) {
            bf16x8 a = *reinterpret_cast<const bf16x8*>(orow + k0);
#pragma unroll
            for (int nt = 0; nt < 4; ++nt) {
                bf16x8 b = *reinterpret_cast<const bf16x8*>(&w_s[nt * 16 + l16][k0 + quad * 8]);
                acc[nt] = __builtin_amdgcn_mfma_f32_16x16x32_bf16(b, a, acc[nt], 0, 0, 0);
            }
        }
        const int m = mh + wav * 16 + l16;
#pragma unroll
        for (int nt = 0; nt < 4; ++nt) {
            const int oc0 = n0 + nt * 16 + quad * 4;
            f32x4 bv = *reinterpret_cast<const f32x4*>(bias + oc0);
            f32x4 ovv = acc[nt] + bv;
            *reinterpret_cast<f32x4*>(out + (size_t)m * C_ + oc0) = ovv;
        }
    }
}

extern "C" void kernel_launch(void* const* d_in, const int* in_sizes, int n_in,
                              void* d_out, int out_size, void* d_ws, size_t ws_size,
                              hipStream_t stream) {
    const float* x      = (const float*)d_in[0];
    const float* w_qkv  = (const float*)d_in[1];
    const float* w_proj = (const float*)d_in[2];
    const float* b_proj = (const float*)d_in[3];
    float* out = (float*)d_out;

    const size_t qkv_elems = (size_t)B_ * H_ * N_ * D_;   // 4,194,304
    bf16* q_ws  = (bf16*)d_ws;
    bf16* k_ws  = q_ws  + qkv_elems;
    f16*  vt_ws = (f16*)(k_ws + qkv_elems);
    bf16* o_ws  = (bf16*)(vt_ws + qkv_elems);
    bf16* x_bf  = o_ws  + qkv_elems;
    bf16* wq_bf = x_bf  + (size_t)B_ * N_ * C_;
    bf16* wp_bf = wq_bf + (size_t)3 * C_ * C_;

    cast_bf16    <<<2176, 256, 0, stream>>>(x, w_qkv, w_proj, x_bf, wq_bf, wp_bf);
    qkv_fast     <<<1536, 256, 0, stream>>>(x_bf, wq_bf, q_ws, k_ws, vt_ws);
    attn         <<<1024, 256, 0, stream>>>(q_ws, k_ws, vt_ws, o_ws);
    out_proj_fast<<< 512, 256, 0, stream>>>(o_ws, wp_bf, b_proj, out);
}

// Round 15
// 177.404 us; speedup vs baseline: 1.0620x; 1.0620x over previous
//
#include <hip/hip_runtime.h>
#include <hip/hip_bf16.h>

typedef __hip_bfloat16 bf16;
typedef _Float16 f16;
typedef __attribute__((ext_vector_type(8))) short bf16x8;
typedef __attribute__((ext_vector_type(8))) _Float16 f16x8;
typedef __attribute__((ext_vector_type(2))) _Float16 f16x2;
typedef __attribute__((ext_vector_type(4))) float f32x4;
typedef __attribute__((ext_vector_type(4))) unsigned int u32x4;
typedef __attribute__((ext_vector_type(2))) unsigned int u32x2;

#define B_ 4
#define N_ 4096
#define C_ 256
#define H_ 4
#define D_ 64
#define KLN 0.18033688011112042f   /* 0.125 * log2(e): folded into Q */

#if __has_builtin(__builtin_amdgcn_exp2f)
#define EXP2(x) __builtin_amdgcn_exp2f(x)
#else
#define EXP2(x) exp2f(x)
#endif
#if __has_builtin(__builtin_amdgcn_rcpf)
#define RCP(x) __builtin_amdgcn_rcpf(x)
#else
#define RCP(x) (1.0f / (x))
#endif

// direct global->LDS DMA, 16B per lane. LDS dest = wave-uniform base + lane*16.
__device__ inline void load_lds16(const void* g, void* l) {
#if __has_builtin(__builtin_amdgcn_global_load_lds)
    __builtin_amdgcn_global_load_lds(
        (const __attribute__((address_space(1))) unsigned int*)g,
        (__attribute__((address_space(3))) unsigned int*)l, 16, 0, 0);
#else
    int ln = __lane_id();
    ((u32x4*)l)[ln] = *((const u32x4*)g);   // fallback (not used on gfx950)
#endif
}

// two fp32 -> packed bf16 pair (round-half-up)
__device__ inline unsigned int pk2(float a, float b) {
    unsigned int ua = __builtin_bit_cast(unsigned int, a) + 0x8000u;
    unsigned int ub = __builtin_bit_cast(unsigned int, b) + 0x8000u;
    return (ua >> 16) | (ub & 0xffff0000u);
}
// two fp32 -> packed f16 pair (single v_cvt_pkrtz_f16_f32)
__device__ inline unsigned int pkh2(float a, float b) {
#if __has_builtin(__builtin_amdgcn_cvt_pkrtz)
    return __builtin_bit_cast(unsigned int, __builtin_amdgcn_cvt_pkrtz(a, b));
#else
    f16x2 h = { (f16)a, (f16)b };
    return __builtin_bit_cast(unsigned int, h);
#endif
}

// ---------------------------------------------------------------------------
// Prep: cast x, w_qkv, w_proj fp32 -> bf16 (memory-bound).
// ---------------------------------------------------------------------------
__global__ __launch_bounds__(256) void cast_bf16(const float* __restrict__ x,
                                                 const float* __restrict__ wq,
                                                 const float* __restrict__ wp,
                                                 bf16* __restrict__ xb,
                                                 bf16* __restrict__ wqb,
                                                 bf16* __restrict__ wpb)
{
    int bid = blockIdx.x;
    const float* s; bf16* d; int base;
    if (bid < 2048)      { s = x;  d = xb;  base = bid * 2048; }
    else if (bid < 2144) { s = wq; d = wqb; base = (bid - 2048) * 2048; }
    else                 { s = wp; d = wpb; base = (bid - 2144) * 2048; }
    int i = base + threadIdx.x * 8;
    f32x4 a = *reinterpret_cast<const f32x4*>(s + i);
    f32x4 b = *reinterpret_cast<const f32x4*>(s + i + 4);
    u32x4 o;
    o.x = pk2(a[0], a[1]); o.y = pk2(a[2], a[3]);
    o.z = pk2(b[0], b[1]); o.w = pk2(b[2], b[3]);
    *reinterpret_cast<u32x4*>(d + i) = o;
}

// ---------------------------------------------------------------------------
// QKV projection — r3 structure with 256-row m-tiles (W staged once per
// 256 rows: 2x better amortization than r3's 128; same lever that measured
// +10us when going 64->128). Grid 768 = 8 XCD x 96.
// ---------------------------------------------------------------------------
__global__ __launch_bounds__(256, 2) void qkv_fast(const bf16* __restrict__ x,
                                                   const bf16* __restrict__ w,
                                                   bf16* __restrict__ qw,
                                                   bf16* __restrict__ kw,
                                                   f16* __restrict__ vtw)
{
    __shared__ short w_s[64][264];
    const int tid  = threadIdx.x;
    const int lane = tid & 63;
    const int wav  = tid >> 6;
    const int quad = lane >> 4;
    const int l16  = lane & 15;
    const int bid = (blockIdx.x & 7) * 96 + (blockIdx.x >> 3);   // 768 = 8*96
    const int mt = bid / 12, nb = bid % 12;
    const int m0 = mt * 256, n0 = nb * 64;

    {
        const int row = tid >> 2, cb = (tid & 3) * 64;
        const bf16* src = w + (size_t)(n0 + row) * C_ + cb;
#pragma unroll
        for (int i = 0; i < 8; ++i)
            *reinterpret_cast<bf16x8*>(&w_s[row][cb + i * 8]) =
                *reinterpret_cast<const bf16x8*>(src + i * 8);
    }
    __syncthreads();

#pragma unroll
    for (int half = 0; half < 4; ++half) {
        const int mh = m0 + half * 64;
        f32x4 acc[4] = {{0,0,0,0},{0,0,0,0},{0,0,0,0},{0,0,0,0}};
        const bf16* xrow = x + (size_t)(mh + wav * 16 + l16) * C_ + quad * 8;
        if (nb < 8) {        // Q/K: transposed accumulator (swapped operands)
#pragma unroll
            for (int k0 = 0; k0 < C_; k0 += 32) {
                bf16x8 a = *reinterpret_cast<const bf16x8*>(xrow + k0);
#pragma unroll
                for (int nt = 0; nt < 4; ++nt) {
                    bf16x8 b = *reinterpret_cast<const bf16x8*>(&w_s[nt * 16 + l16][k0 + quad * 8]);
                    acc[nt] = __builtin_amdgcn_mfma_f32_16x16x32_bf16(b, a, acc[nt], 0, 0, 0);
                }
            }
        } else {             // V: normal orientation (store wants n-contiguous)
#pragma unroll
            for (int k0 = 0; k0 < C_; k0 += 32) {
                bf16x8 a = *reinterpret_cast<const bf16x8*>(xrow + k0);
#pragma unroll
                for (int nt = 0; nt < 4; ++nt) {
                    bf16x8 b = *reinterpret_cast<const bf16x8*>(&w_s[nt * 16 + l16][k0 + quad * 8]);
                    acc[nt] = __builtin_amdgcn_mfma_f32_16x16x32_bf16(a, b, acc[nt], 0, 0, 0);
                }
            }
        }

        const int bb = mh >> 12;
        const int nbase = (mh + wav * 16) & (N_ - 1);
        if (nb < 4) {                            // Q (scaled): row n = nbase+l16
            bf16* dst = qw + (((size_t)bb * H_ + nb) * N_ + nbase + l16) * D_;
#pragma unroll
            for (int nt = 0; nt < 4; ++nt) {
                u32x2 wv = { pk2(acc[nt][0] * KLN, acc[nt][1] * KLN),
                             pk2(acc[nt][2] * KLN, acc[nt][3] * KLN) };
                *reinterpret_cast<u32x2*>(dst + nt * 16 + quad * 4) = wv;
            }
        } else if (nb < 8) {                     // K
            bf16* dst = kw + (((size_t)bb * H_ + (nb - 4)) * N_ + nbase + l16) * D_;
#pragma unroll
            for (int nt = 0; nt < 4; ++nt) {
                u32x2 wv = { pk2(acc[nt][0], acc[nt][1]),
                             pk2(acc[nt][2], acc[nt][3]) };
                *reinterpret_cast<u32x2*>(dst + nt * 16 + quad * 4) = wv;
            }
        } else {                                 // V transposed, f16
            const int h = nb - 8;
#pragma unroll
            for (int nt = 0; nt < 4; ++nt) {
                int d = nt * 16 + l16;
                u32x2 wv;
                wv.x = pkh2(acc[nt][0], acc[nt][1]);
                wv.y = pkh2(acc[nt][2], acc[nt][3]);
                *reinterpret_cast<u32x2*>(
                    vtw + (((size_t)bb * H_ + h) * D_ + d) * N_ + nbase + quad * 4) = wv;
            }
        }
    }
}

// ---------------------------------------------------------------------------
// Flash attention — EXACT round-7 kernel (best measured: 72.2us, session
// best total 172.0). r1 structure: 512-thr 8-wave blocks, 2 q-groups/wave,
// K+V LDS double-buffer, one __syncthreads/tile, in-register P via pi K-row
// permutation, l via ones-MFMA, j-half merge through LDS. Rounds 2-14
// explored 8 structural variants (setprio, 4 q-groups, global->reg, counted
// vmcnt, manual unroll, cross-tile PV pipeline at 2 occupancies): all landed
// 73.6-133.8us. This configuration is the measured optimum.
// ---------------------------------------------------------------------------
__global__ __launch_bounds__(512, 4) void attn(const bf16* __restrict__ q,
                                               const bf16* __restrict__ k,
                                               const f16* __restrict__ vt,
                                               bf16* __restrict__ o)
{
    __shared__ __align__(16) char smem[65536];
    short* k_s = reinterpret_cast<short*>(smem);            // [buf][jh][64*64]
    f16*   v_s = reinterpret_cast<f16*>(smem + 32768);      // [buf][jh][64*64]

    const int tid  = threadIdx.x;
    const int lane = tid & 63;
    const int wav  = tid >> 6;       // 0..7
    const int quad = lane >> 4;
    const int l16  = lane & 15;
    const int l8   = lane & 7;
    const int sub  = wav & 3;        // 32-row q-slice within the 128-row tile
    const int jh   = wav >> 2;       // j-half

    const int wg = (blockIdx.x & 7) * 64 + (blockIdx.x >> 3);  // XCD swizzle
    const int bh = wg >> 5;
    const int qt = wg & 31;
    const int bb = bh >> 2, h = bh & 3;

    const bf16* qp = q  + (size_t)bh * N_ * D_;
    const bf16* kp = k  + (size_t)bh * N_ * D_;
    const f16*  vp = vt + (size_t)bh * D_ * N_;

    const int qbase = qt * 128 + sub * 32;
    bf16x8 qb[2][2];
#pragma unroll
    for (int qg = 0; qg < 2; ++qg)
#pragma unroll
        for (int ks = 0; ks < 2; ++ks)
            qb[qg][ks] = *reinterpret_cast<const bf16x8*>(
                qp + (size_t)(qbase + qg * 16 + l16) * D_ + ks * 32 + quad * 8);

    // staging geometry: lane -> (row ri, stored slot ci); logical chunk = ci^ri
    const int ri = lane >> 3;
    const int ci = lane & 7;
    const int gc = ci ^ ri;
    int koff[2], voff[2], lds_r[2];
#pragma unroll
    for (int g = 0; g < 2; ++g) {
        const int rb  = sub * 16 + g * 8;
        const int rho = rb + ri;
        const int pr  = (rho & 32) | ((rho & 12) << 1) | ((rho & 16) >> 2) | (rho & 3);
        koff[g]  = pr * D_ + gc * 8;          // K: permuted row, swizzled chunk
        voff[g]  = rho * N_ + gc * 8;         // V: linear d-row, swizzled chunk
        lds_r[g] = rb * 64;
    }

    f32x4 oacc[2][4];
    f32x4 lacc[2];
#pragma unroll
    for (int qg = 0; qg < 2; ++qg) {
        lacc[qg] = (f32x4){0, 0, 0, 0};
#pragma unroll
        for (int dt = 0; dt < 4; ++dt) oacc[qg][dt] = (f32x4){0, 0, 0, 0};
    }
    const f16x8 onesA = {1.f16, 1.f16, 1.f16, 1.f16, 1.f16, 1.f16, 1.f16, 1.f16};

    auto stage = [&](int buf, int t) {
        const int j0 = jh * 2048 + t * 64;
        short* kd = k_s + (size_t)(buf * 2 + jh) * 4096;
        f16*   vd = v_s + (size_t)(buf * 2 + jh) * 4096;
#pragma unroll
        for (int g = 0; g < 2; ++g) {
            load_lds16(kp + (size_t)j0 * D_ + koff[g], kd + lds_r[g]);
            load_lds16(vp + j0 + voff[g],              vd + lds_r[g]);
        }
    };

    stage(0, 0);
    __syncthreads();

    for (int t = 0; t < 32; ++t) {
        const int cur = t & 1;
        if (t < 31) stage(cur ^ 1, t + 1);    // DMA overlaps this tile's compute

        const short* kt  = k_s + (size_t)(cur * 2 + jh) * 4096;
        const f16*   vtl = v_s + (size_t)(cur * 2 + jh) * 4096;

        // K fragments (shared across both q-groups)
        bf16x8 ka[4][2];
#pragma unroll
        for (int nt = 0; nt < 4; ++nt) {
            const int rb = (nt * 16 + l16) * 64;
            ka[nt][0] = *reinterpret_cast<const bf16x8*>(kt + rb + ((quad    ) ^ l8) * 8);
            ka[nt][1] = *reinterpret_cast<const bf16x8*>(kt + rb + ((4 + quad) ^ l8) * 8);
        }

        f32x4 s[4];
        f16x8 pb0[2], pb1[2];

        // --- QK(0) ---
#pragma unroll
        for (int nt = 0; nt < 4; ++nt) {
            s[nt] = __builtin_amdgcn_mfma_f32_16x16x32_bf16(
                ka[nt][0], qb[0][0], (f32x4){0.f, 0.f, 0.f, 0.f}, 0, 0, 0);
            s[nt] = __builtin_amdgcn_mfma_f32_16x16x32_bf16(
                ka[nt][1], qb[0][1], s[nt], 0, 0, 0);
        }
        // --- exp(0) + l(0) ---
#pragma unroll
        for (int ks = 0; ks < 2; ++ks) {
            const f32x4 sa = s[2 * ks], sb = s[2 * ks + 1];
            u32x4 pw;
            pw.x = pkh2(EXP2(sa[0]), EXP2(sa[1]));
            pw.y = pkh2(EXP2(sa[2]), EXP2(sa[3]));
            pw.z = pkh2(EXP2(sb[0]), EXP2(sb[1]));
            pw.w = pkh2(EXP2(sb[2]), EXP2(sb[3]));
            pb0[ks] = __builtin_bit_cast(f16x8, pw);
            lacc[0] = __builtin_amdgcn_mfma_f32_16x16x32_f16(onesA, pb0[ks], lacc[0], 0, 0, 0);
        }
        // --- QK(1) (matrix; independent of exp(0)/PV(0)) ---
#pragma unroll
        for (int nt = 0; nt < 4; ++nt) {
            s[nt] = __builtin_amdgcn_mfma_f32_16x16x32_bf16(
                ka[nt][0], qb[1][0], (f32x4){0.f, 0.f, 0.f, 0.f}, 0, 0, 0);
            s[nt] = __builtin_amdgcn_mfma_f32_16x16x32_bf16(
                ka[nt][1], qb[1][1], s[nt], 0, 0, 0);
        }
        // --- PV(0) (matrix; queues behind QK(1)) ---
#pragma unroll
        for (int ks = 0; ks < 2; ++ks)
#pragma unroll
            for (int dt = 0; dt < 4; ++dt) {
                f16x8 va = *reinterpret_cast<const f16x8*>(
                    vtl + (dt * 16 + l16) * 64 + (((ks << 2) + quad) ^ l8) * 8);
                oacc[0][dt] = __builtin_amdgcn_mfma_f32_16x16x32_f16(va, pb0[ks], oacc[0][dt], 0, 0, 0);
            }
        // --- exp(1) + l(1) (VALU; executes under the QK(1)+PV(0) backlog) ---
#pragma unroll
        for (int ks = 0; ks < 2; ++ks) {
            const f32x4 sa = s[2 * ks], sb = s[2 * ks + 1];
            u32x4 pw;
            pw.x = pkh2(EXP2(sa[0]), EXP2(sa[1]));
            pw.y = pkh2(EXP2(sa[2]), EXP2(sa[3]));
            pw.z = pkh2(EXP2(sb[0]), EXP2(sb[1]));
            pw.w = pkh2(EXP2(sb[2]), EXP2(sb[3]));
            pb1[ks] = __builtin_bit_cast(f16x8, pw);
            lacc[1] = __builtin_amdgcn_mfma_f32_16x16x32_f16(onesA, pb1[ks], lacc[1], 0, 0, 0);
        }
        // --- PV(1) (matrix; executes under next tile's staging + reads) ---
#pragma unroll
        for (int ks = 0; ks < 2; ++ks)
#pragma unroll
            for (int dt = 0; dt < 4; ++dt) {
                f16x8 va = *reinterpret_cast<const f16x8*>(
                    vtl + (dt * 16 + l16) * 64 + (((ks << 2) + quad) ^ l8) * 8);
                oacc[1][dt] = __builtin_amdgcn_mfma_f32_16x16x32_f16(va, pb1[ks], oacc[1][dt], 0, 0, 0);
            }

        __syncthreads();   // drains this wave's DMA (t+1) + fences buf reads
    }

    // ---- merge j-halves (exact: O and l add) via lane-to-lane LDS slots ----
    __syncthreads();                  // staging reads done; reuse as merge buf
    float* mrg = reinterpret_cast<float*>(smem);
    const int slot = (sub * 64 + lane) * 35;       // odd stride: no conflicts
    if (jh == 1) {
#pragma unroll
        for (int qg = 0; qg < 2; ++qg) {
#pragma unroll
            for (int dt = 0; dt < 4; ++dt)
#pragma unroll
                for (int e = 0; e < 4; ++e)
                    mrg[slot + qg * 17 + dt * 4 + e] = oacc[qg][dt][e];
            mrg[slot + qg * 17 + 16] = lacc[qg][0];
        }
    }
    __syncthreads();
    if (jh == 0) {
#pragma unroll
        for (int qg = 0; qg < 2; ++qg) {
            const float rl = RCP(lacc[qg][0] + mrg[slot + qg * 17 + 16]);
            const size_t obase = ((size_t)bb * N_ + qbase + qg * 16 + l16) * C_ + h * D_;
#pragma unroll
            for (int dt = 0; dt < 4; ++dt) {
                float v0 = (oacc[qg][dt][0] + mrg[slot + qg * 17 + dt * 4 + 0]) * rl;
                float v1 = (oacc[qg][dt][1] + mrg[slot + qg * 17 + dt * 4 + 1]) * rl;
                float v2 = (oacc[qg][dt][2] + mrg[slot + qg * 17 + dt * 4 + 2]) * rl;
                float v3 = (oacc[qg][dt][3] + mrg[slot + qg * 17 + dt * 4 + 3]) * rl;
                u32x2 wv = { pk2(v0, v1), pk2(v2, v3) };
                *reinterpret_cast<u32x2*>(o + obase + dt * 16 + quad * 4) = wv;
            }
        }
    }
}

// ---------------------------------------------------------------------------
// Output projection — round-3 version (best measured).
// ---------------------------------------------------------------------------
__global__ __launch_bounds__(256, 2) void out_proj_fast(const bf16* __restrict__ ov,
                                                        const bf16* __restrict__ w,
                                                        const float* __restrict__ bias,
                                                        float* __restrict__ out)
{
    __shared__ short w_s[64][264];
    const int tid  = threadIdx.x;
    const int lane = tid & 63;
    const int wav  = tid >> 6;
    const int quad = lane >> 4;
    const int l16  = lane & 15;
    const int bid = (blockIdx.x & 7) * 64 + (blockIdx.x >> 3);   // 512 = 8*64
    const int m0 = (bid >> 2) * 128;
    const int n0 = (bid & 3) * 64;

    {
        const int row = tid >> 2, cb = (tid & 3) * 64;
        const bf16* src = w + (size_t)(n0 + row) * C_ + cb;
#pragma unroll
        for (int i = 0; i < 8; ++i)
            *reinterpret_cast<bf16x8*>(&w_s[row][cb + i * 8]) =
                *reinterpret_cast<const bf16x8*>(src + i * 8);
    }
    __syncthreads();

#pragma unroll
    for (int half = 0; half < 2; ++half) {
        const int mh = m0 + half * 64;
        f32x4 acc[4] = {{0,0,0,0},{0,0,0,0},{0,0,0,0},{0,0,0,0}};
        const bf16* orow = ov + (size_t)(mh + wav * 16 + l16) * C_ + quad * 8;
#pragma unroll
        for (int k0 = 0; k0 < C_; k0 += 32) {
            bf16x8 a = *reinterpret_cast<const bf16x8*>(orow + k0);
#pragma unroll
            for (int nt = 0; nt < 4; ++nt) {
                bf16x8 b = *reinterpret_cast<const bf16x8*>(&w_s[nt * 16 + l16][k0 + quad * 8]);
                acc[nt] = __builtin_amdgcn_mfma_f32_16x16x32_bf16(b, a, acc[nt], 0, 0, 0);
            }
        }
        const int m = mh + wav * 16 + l16;
#pragma unroll
        for (int nt = 0; nt < 4; ++nt) {
            const int oc0 = n0 + nt * 16 + quad * 4;
            f32x4 bv = *reinterpret_cast<const f32x4*>(bias + oc0);
            f32x4 ovv = acc[nt] + bv;
            *reinterpret_cast<f32x4*>(out + (size_t)m * C_ + oc0) = ovv;
        }
    }
}

extern "C" void kernel_launch(void* const* d_in, const int* in_sizes, int n_in,
                              void* d_out, int out_size, void* d_ws, size_t ws_size,
                              hipStream_t stream) {
    const float* x      = (const float*)d_in[0];
    const float* w_qkv  = (const float*)d_in[1];
    const float* w_proj = (const float*)d_in[2];
    const float* b_proj = (const float*)d_in[3];
    float* out = (float*)d_out;

    const size_t qkv_elems = (size_t)B_ * H_ * N_ * D_;   // 4,194,304
    bf16* q_ws  = (bf16*)d_ws;
    bf16* k_ws  = q_ws  + qkv_elems;
    f16*  vt_ws = (f16*)(k_ws + qkv_elems);
    bf16* o_ws  = (bf16*)(vt_ws + qkv_elems);
    bf16* x_bf  = o_ws  + qkv_elems;
    bf16* wq_bf = x_bf  + (size_t)B_ * N_ * C_;
    bf16* wp_bf = wq_bf + (size_t)3 * C_ * C_;

    cast_bf16    <<<2176, 256, 0, stream>>>(x, w_qkv, w_proj, x_bf, wq_bf, wp_bf);
    qkv_fast     <<< 768, 256, 0, stream>>>(x_bf, wq_bf, q_ws, k_ws, vt_ws);
    attn         <<< 512, 512, 0, stream>>>(q_ws, k_ws, vt_ws, o_ws);
    out_proj_fast<<< 512, 256, 0, stream>>>(o_ws, wp_bf, b_proj, out);
}

// Round 16
// 173.983 us; speedup vs baseline: 1.0829x; 1.0197x over previous
//
#include <hip/hip_runtime.h>
#include <hip/hip_bf16.h>

typedef __hip_bfloat16 bf16;
typedef _Float16 f16;
typedef __attribute__((ext_vector_type(8))) short bf16x8;
typedef __attribute__((ext_vector_type(8))) _Float16 f16x8;
typedef __attribute__((ext_vector_type(2))) _Float16 f16x2;
typedef __attribute__((ext_vector_type(4))) float f32x4;
typedef __attribute__((ext_vector_type(4))) unsigned int u32x4;
typedef __attribute__((ext_vector_type(2))) unsigned int u32x2;

#define B_ 4
#define N_ 4096
#define C_ 256
#define H_ 4
#define D_ 64
#define KLN 0.18033688011112042f   /* 0.125 * log2(e): folded into Q */

#if __has_builtin(__builtin_amdgcn_exp2f)
#define EXP2(x) __builtin_amdgcn_exp2f(x)
#else
#define EXP2(x) exp2f(x)
#endif
#if __has_builtin(__builtin_amdgcn_rcpf)
#define RCP(x) __builtin_amdgcn_rcpf(x)
#else
#define RCP(x) (1.0f / (x))
#endif

// direct global->LDS DMA, 16B per lane. LDS dest = wave-uniform base + lane*16.
__device__ inline void load_lds16(const void* g, void* l) {
#if __has_builtin(__builtin_amdgcn_global_load_lds)
    __builtin_amdgcn_global_load_lds(
        (const __attribute__((address_space(1))) unsigned int*)g,
        (__attribute__((address_space(3))) unsigned int*)l, 16, 0, 0);
#else
    int ln = __lane_id();
    ((u32x4*)l)[ln] = *((const u32x4*)g);   // fallback (not used on gfx950)
#endif
}

// two fp32 -> packed bf16 pair (round-half-up)
__device__ inline unsigned int pk2(float a, float b) {
    unsigned int ua = __builtin_bit_cast(unsigned int, a) + 0x8000u;
    unsigned int ub = __builtin_bit_cast(unsigned int, b) + 0x8000u;
    return (ua >> 16) | (ub & 0xffff0000u);
}
// two fp32 -> packed f16 pair (single v_cvt_pkrtz_f16_f32)
__device__ inline unsigned int pkh2(float a, float b) {
#if __has_builtin(__builtin_amdgcn_cvt_pkrtz)
    return __builtin_bit_cast(unsigned int, __builtin_amdgcn_cvt_pkrtz(a, b));
#else
    f16x2 h = { (f16)a, (f16)b };
    return __builtin_bit_cast(unsigned int, h);
#endif
}

// ---------------------------------------------------------------------------
// Prep: cast x, w_qkv, w_proj fp32 -> bf16 (memory-bound).
// ---------------------------------------------------------------------------
__global__ __launch_bounds__(256) void cast_bf16(const float* __restrict__ x,
                                                 const float* __restrict__ wq,
                                                 const float* __restrict__ wp,
                                                 bf16* __restrict__ xb,
                                                 bf16* __restrict__ wqb,
                                                 bf16* __restrict__ wpb)
{
    int bid = blockIdx.x;
    const float* s; bf16* d; int base;
    if (bid < 2048)      { s = x;  d = xb;  base = bid * 2048; }
    else if (bid < 2144) { s = wq; d = wqb; base = (bid - 2048) * 2048; }
    else                 { s = wp; d = wpb; base = (bid - 2144) * 2048; }
    int i = base + threadIdx.x * 8;
    f32x4 a = *reinterpret_cast<const f32x4*>(s + i);
    f32x4 b = *reinterpret_cast<const f32x4*>(s + i + 4);
    u32x4 o;
    o.x = pk2(a[0], a[1]); o.y = pk2(a[2], a[3]);
    o.z = pk2(b[0], b[1]); o.w = pk2(b[2], b[3]);
    *reinterpret_cast<u32x4*>(d + i) = o;
}

// ---------------------------------------------------------------------------
// QKV projection — round-3 version (best measured: 128-row m-tiles, grid
// 1536 = 6 full waves of 2 blocks/CU, no tail; r15's 256-row variant
// regressed ~5us from its 256-block tail wave).
// ---------------------------------------------------------------------------
__global__ __launch_bounds__(256, 2) void qkv_fast(const bf16* __restrict__ x,
                                                   const bf16* __restrict__ w,
                                                   bf16* __restrict__ qw,
                                                   bf16* __restrict__ kw,
                                                   f16* __restrict__ vtw)
{
    __shared__ short w_s[64][264];
    const int tid  = threadIdx.x;
    const int lane = tid & 63;
    const int wav  = tid >> 6;
    const int quad = lane >> 4;
    const int l16  = lane & 15;
    const int bid = (blockIdx.x & 7) * 192 + (blockIdx.x >> 3);   // 1536 = 8*192
    const int mt = bid / 12, nb = bid % 12;
    const int m0 = mt * 128, n0 = nb * 64;

    {
        const int row = tid >> 2, cb = (tid & 3) * 64;
        const bf16* src = w + (size_t)(n0 + row) * C_ + cb;
#pragma unroll
        for (int i = 0; i < 8; ++i)
            *reinterpret_cast<bf16x8*>(&w_s[row][cb + i * 8]) =
                *reinterpret_cast<const bf16x8*>(src + i * 8);
    }
    __syncthreads();

#pragma unroll
    for (int half = 0; half < 2; ++half) {
        const int mh = m0 + half * 64;
        f32x4 acc[4] = {{0,0,0,0},{0,0,0,0},{0,0,0,0},{0,0,0,0}};
        const bf16* xrow = x + (size_t)(mh + wav * 16 + l16) * C_ + quad * 8;
        if (nb < 8) {        // Q/K: transposed accumulator (swapped operands)
#pragma unroll
            for (int k0 = 0; k0 < C_; k0 += 32) {
                bf16x8 a = *reinterpret_cast<const bf16x8*>(xrow + k0);
#pragma unroll
                for (int nt = 0; nt < 4; ++nt) {
                    bf16x8 b = *reinterpret_cast<const bf16x8*>(&w_s[nt * 16 + l16][k0 + quad * 8]);
                    acc[nt] = __builtin_amdgcn_mfma_f32_16x16x32_bf16(b, a, acc[nt], 0, 0, 0);
                }
            }
        } else {             // V: normal orientation (store wants n-contiguous)
#pragma unroll
            for (int k0 = 0; k0 < C_; k0 += 32) {
                bf16x8 a = *reinterpret_cast<const bf16x8*>(xrow + k0);
#pragma unroll
                for (int nt = 0; nt < 4; ++nt) {
                    bf16x8 b = *reinterpret_cast<const bf16x8*>(&w_s[nt * 16 + l16][k0 + quad * 8]);
                    acc[nt] = __builtin_amdgcn_mfma_f32_16x16x32_bf16(a, b, acc[nt], 0, 0, 0);
                }
            }
        }

        const int bb = mh >> 12;
        const int nbase = (mh + wav * 16) & (N_ - 1);
        if (nb < 4) {                            // Q (scaled): row n = nbase+l16
            bf16* dst = qw + (((size_t)bb * H_ + nb) * N_ + nbase + l16) * D_;
#pragma unroll
            for (int nt = 0; nt < 4; ++nt) {
                u32x2 wv = { pk2(acc[nt][0] * KLN, acc[nt][1] * KLN),
                             pk2(acc[nt][2] * KLN, acc[nt][3] * KLN) };
                *reinterpret_cast<u32x2*>(dst + nt * 16 + quad * 4) = wv;
            }
        } else if (nb < 8) {                     // K
            bf16* dst = kw + (((size_t)bb * H_ + (nb - 4)) * N_ + nbase + l16) * D_;
#pragma unroll
            for (int nt = 0; nt < 4; ++nt) {
                u32x2 wv = { pk2(acc[nt][0], acc[nt][1]),
                             pk2(acc[nt][2], acc[nt][3]) };
                *reinterpret_cast<u32x2*>(dst + nt * 16 + quad * 4) = wv;
            }
        } else {                                 // V transposed, f16
            const int h = nb - 8;
#pragma unroll
            for (int nt = 0; nt < 4; ++nt) {
                int d = nt * 16 + l16;
                u32x2 wv;
                wv.x = pkh2(acc[nt][0], acc[nt][1]);
                wv.y = pkh2(acc[nt][2], acc[nt][3]);
                *reinterpret_cast<u32x2*>(
                    vtw + (((size_t)bb * H_ + h) * D_ + d) * N_ + nbase + quad * 4) = wv;
            }
        }
    }
}

// ---------------------------------------------------------------------------
// Flash attention — EXACT round-7 kernel (best measured: 72.2us, session
// best total 172.0). r1 structure: 512-thr 8-wave blocks, 2 q-groups/wave,
// K+V LDS double-buffer, one __syncthreads/tile, in-register P via pi K-row
// permutation, l via ones-MFMA, j-half merge through LDS. Rounds 2-14
// explored 10 structural variants (setprio, l->VALU, 4 q-groups,
// global->reg, K-LDS/V-reg + counted vmcnt, manual unroll, reorder,
// cross-tile PV pipeline at 2 and 4 waves/SIMD independence): all landed
// 73.6-133.8us. This configuration is the measured optimum.
// ---------------------------------------------------------------------------
__global__ __launch_bounds__(512, 4) void attn(const bf16* __restrict__ q,
                                               const bf16* __restrict__ k,
                                               const f16* __restrict__ vt,
                                               bf16* __restrict__ o)
{
    __shared__ __align__(16) char smem[65536];
    short* k_s = reinterpret_cast<short*>(smem);            // [buf][jh][64*64]
    f16*   v_s = reinterpret_cast<f16*>(smem + 32768);      // [buf][jh][64*64]

    const int tid  = threadIdx.x;
    const int lane = tid & 63;
    const int wav  = tid >> 6;       // 0..7
    const int quad = lane >> 4;
    const int l16  = lane & 15;
    const int l8   = lane & 7;
    const int sub  = wav & 3;        // 32-row q-slice within the 128-row tile
    const int jh   = wav >> 2;       // j-half

    const int wg = (blockIdx.x & 7) * 64 + (blockIdx.x >> 3);  // XCD swizzle
    const int bh = wg >> 5;
    const int qt = wg & 31;
    const int bb = bh >> 2, h = bh & 3;

    const bf16* qp = q  + (size_t)bh * N_ * D_;
    const bf16* kp = k  + (size_t)bh * N_ * D_;
    const f16*  vp = vt + (size_t)bh * D_ * N_;

    const int qbase = qt * 128 + sub * 32;
    bf16x8 qb[2][2];
#pragma unroll
    for (int qg = 0; qg < 2; ++qg)
#pragma unroll
        for (int ks = 0; ks < 2; ++ks)
            qb[qg][ks] = *reinterpret_cast<const bf16x8*>(
                qp + (size_t)(qbase + qg * 16 + l16) * D_ + ks * 32 + quad * 8);

    // staging geometry: lane -> (row ri, stored slot ci); logical chunk = ci^ri
    const int ri = lane >> 3;
    const int ci = lane & 7;
    const int gc = ci ^ ri;
    int koff[2], voff[2], lds_r[2];
#pragma unroll
    for (int g = 0; g < 2; ++g) {
        const int rb  = sub * 16 + g * 8;
        const int rho = rb + ri;
        const int pr  = (rho & 32) | ((rho & 12) << 1) | ((rho & 16) >> 2) | (rho & 3);
        koff[g]  = pr * D_ + gc * 8;          // K: permuted row, swizzled chunk
        voff[g]  = rho * N_ + gc * 8;         // V: linear d-row, swizzled chunk
        lds_r[g] = rb * 64;
    }

    f32x4 oacc[2][4];
    f32x4 lacc[2];
#pragma unroll
    for (int qg = 0; qg < 2; ++qg) {
        lacc[qg] = (f32x4){0, 0, 0, 0};
#pragma unroll
        for (int dt = 0; dt < 4; ++dt) oacc[qg][dt] = (f32x4){0, 0, 0, 0};
    }
    const f16x8 onesA = {1.f16, 1.f16, 1.f16, 1.f16, 1.f16, 1.f16, 1.f16, 1.f16};

    auto stage = [&](int buf, int t) {
        const int j0 = jh * 2048 + t * 64;
        short* kd = k_s + (size_t)(buf * 2 + jh) * 4096;
        f16*   vd = v_s + (size_t)(buf * 2 + jh) * 4096;
#pragma unroll
        for (int g = 0; g < 2; ++g) {
            load_lds16(kp + (size_t)j0 * D_ + koff[g], kd + lds_r[g]);
            load_lds16(vp + j0 + voff[g],              vd + lds_r[g]);
        }
    };

    stage(0, 0);
    __syncthreads();

    for (int t = 0; t < 32; ++t) {
        const int cur = t & 1;
        if (t < 31) stage(cur ^ 1, t + 1);    // DMA overlaps this tile's compute

        const short* kt  = k_s + (size_t)(cur * 2 + jh) * 4096;
        const f16*   vtl = v_s + (size_t)(cur * 2 + jh) * 4096;

        // K fragments (shared across both q-groups)
        bf16x8 ka[4][2];
#pragma unroll
        for (int nt = 0; nt < 4; ++nt) {
            const int rb = (nt * 16 + l16) * 64;
            ka[nt][0] = *reinterpret_cast<const bf16x8*>(kt + rb + ((quad    ) ^ l8) * 8);
            ka[nt][1] = *reinterpret_cast<const bf16x8*>(kt + rb + ((4 + quad) ^ l8) * 8);
        }

        f32x4 s[4];
        f16x8 pb0[2], pb1[2];

        // --- QK(0) ---
#pragma unroll
        for (int nt = 0; nt < 4; ++nt) {
            s[nt] = __builtin_amdgcn_mfma_f32_16x16x32_bf16(
                ka[nt][0], qb[0][0], (f32x4){0.f, 0.f, 0.f, 0.f}, 0, 0, 0);
            s[nt] = __builtin_amdgcn_mfma_f32_16x16x32_bf16(
                ka[nt][1], qb[0][1], s[nt], 0, 0, 0);
        }
        // --- exp(0) + l(0) ---
#pragma unroll
        for (int ks = 0; ks < 2; ++ks) {
            const f32x4 sa = s[2 * ks], sb = s[2 * ks + 1];
            u32x4 pw;
            pw.x = pkh2(EXP2(sa[0]), EXP2(sa[1]));
            pw.y = pkh2(EXP2(sa[2]), EXP2(sa[3]));
            pw.z = pkh2(EXP2(sb[0]), EXP2(sb[1]));
            pw.w = pkh2(EXP2(sb[2]), EXP2(sb[3]));
            pb0[ks] = __builtin_bit_cast(f16x8, pw);
            lacc[0] = __builtin_amdgcn_mfma_f32_16x16x32_f16(onesA, pb0[ks], lacc[0], 0, 0, 0);
        }
        // --- QK(1) (matrix; independent of exp(0)/PV(0)) ---
#pragma unroll
        for (int nt = 0; nt < 4; ++nt) {
            s[nt] = __builtin_amdgcn_mfma_f32_16x16x32_bf16(
                ka[nt][0], qb[1][0], (f32x4){0.f, 0.f, 0.f, 0.f}, 0, 0, 0);
            s[nt] = __builtin_amdgcn_mfma_f32_16x16x32_bf16(
                ka[nt][1], qb[1][1], s[nt], 0, 0, 0);
        }
        // --- PV(0) (matrix; queues behind QK(1)) ---
#pragma unroll
        for (int ks = 0; ks < 2; ++ks)
#pragma unroll
            for (int dt = 0; dt < 4; ++dt) {
                f16x8 va = *reinterpret_cast<const f16x8*>(
                    vtl + (dt * 16 + l16) * 64 + (((ks << 2) + quad) ^ l8) * 8);
                oacc[0][dt] = __builtin_amdgcn_mfma_f32_16x16x32_f16(va, pb0[ks], oacc[0][dt], 0, 0, 0);
            }
        // --- exp(1) + l(1) (VALU; executes under the QK(1)+PV(0) backlog) ---
#pragma unroll
        for (int ks = 0; ks < 2; ++ks) {
            const f32x4 sa = s[2 * ks], sb = s[2 * ks + 1];
            u32x4 pw;
            pw.x = pkh2(EXP2(sa[0]), EXP2(sa[1]));
            pw.y = pkh2(EXP2(sa[2]), EXP2(sa[3]));
            pw.z = pkh2(EXP2(sb[0]), EXP2(sb[1]));
            pw.w = pkh2(EXP2(sb[2]), EXP2(sb[3]));
            pb1[ks] = __builtin_bit_cast(f16x8, pw);
            lacc[1] = __builtin_amdgcn_mfma_f32_16x16x32_f16(onesA, pb1[ks], lacc[1], 0, 0, 0);
        }
        // --- PV(1) (matrix; executes under next tile's staging + reads) ---
#pragma unroll
        for (int ks = 0; ks < 2; ++ks)
#pragma unroll
            for (int dt = 0; dt < 4; ++dt) {
                f16x8 va = *reinterpret_cast<const f16x8*>(
                    vtl + (dt * 16 + l16) * 64 + (((ks << 2) + quad) ^ l8) * 8);
                oacc[1][dt] = __builtin_amdgcn_mfma_f32_16x16x32_f16(va, pb1[ks], oacc[1][dt], 0, 0, 0);
            }

        __syncthreads();   // drains this wave's DMA (t+1) + fences buf reads
    }

    // ---- merge j-halves (exact: O and l add) via lane-to-lane LDS slots ----
    __syncthreads();                  // staging reads done; reuse as merge buf
    float* mrg = reinterpret_cast<float*>(smem);
    const int slot = (sub * 64 + lane) * 35;       // odd stride: no conflicts
    if (jh == 1) {
#pragma unroll
        for (int qg = 0; qg < 2; ++qg) {
#pragma unroll
            for (int dt = 0; dt < 4; ++dt)
#pragma unroll
                for (int e = 0; e < 4; ++e)
                    mrg[slot + qg * 17 + dt * 4 + e] = oacc[qg][dt][e];
            mrg[slot + qg * 17 + 16] = lacc[qg][0];
        }
    }
    __syncthreads();
    if (jh == 0) {
#pragma unroll
        for (int qg = 0; qg < 2; ++qg) {
            const float rl = RCP(lacc[qg][0] + mrg[slot + qg * 17 + 16]);
            const size_t obase = ((size_t)bb * N_ + qbase + qg * 16 + l16) * C_ + h * D_;
#pragma unroll
            for (int dt = 0; dt < 4; ++dt) {
                float v0 = (oacc[qg][dt][0] + mrg[slot + qg * 17 + dt * 4 + 0]) * rl;
                float v1 = (oacc[qg][dt][1] + mrg[slot + qg * 17 + dt * 4 + 1]) * rl;
                float v2 = (oacc[qg][dt][2] + mrg[slot + qg * 17 + dt * 4 + 2]) * rl;
                float v3 = (oacc[qg][dt][3] + mrg[slot + qg * 17 + dt * 4 + 3]) * rl;
                u32x2 wv = { pk2(v0, v1), pk2(v2, v3) };
                *reinterpret_cast<u32x2*>(o + obase + dt * 16 + quad * 4) = wv;
            }
        }
    }
}

// ---------------------------------------------------------------------------
// Output projection — round-3 version (best measured).
// ---------------------------------------------------------------------------
__global__ __launch_bounds__(256, 2) void out_proj_fast(const bf16* __restrict__ ov,
                                                        const bf16* __restrict__ w,
                                                        const float* __restrict__ bias,
                                                        float* __restrict__ out)
{
    __shared__ short w_s[64][264];
    const int tid  = threadIdx.x;
    const int lane = tid & 63;
    const int wav  = tid >> 6;
    const int quad = lane >> 4;
    const int l16  = lane & 15;
    const int bid = (blockIdx.x & 7) * 64 + (blockIdx.x >> 3);   // 512 = 8*64
    const int m0 = (bid >> 2) * 128;
    const int n0 = (bid & 3) * 64;

    {
        const int row = tid >> 2, cb = (tid & 3) * 64;
        const bf16* src = w + (size_t)(n0 + row) * C_ + cb;
#pragma unroll
        for (int i = 0; i < 8; ++i)
            *reinterpret_cast<bf16x8*>(&w_s[row][cb + i * 8]) =
                *reinterpret_cast<const bf16x8*>(src + i * 8);
    }
    __syncthreads();

#pragma unroll
    for (int half = 0; half < 2; ++half) {
        const int mh = m0 + half * 64;
        f32x4 acc[4] = {{0,0,0,0},{0,0,0,0},{0,0,0,0},{0,0,0,0}};
        const bf16* orow = ov + (size_t)(mh + wav * 16 + l16) * C_ + quad * 8;
#pragma unroll
        for (int k0 = 0; k0 < C_; k0 += 32) {
            bf16x8 a = *reinterpret_cast<const bf16x8*>(orow + k0);
#pragma unroll
            for (int nt = 0; nt < 4; ++nt) {
                bf16x8 b = *reinterpret_cast<const bf16x8*>(&w_s[nt * 16 + l16][k0 + quad * 8]);
                acc[nt] = __builtin_amdgcn_mfma_f32_16x16x32_bf16(b, a, acc[nt], 0, 0, 0);
            }
        }
        const int m = mh + wav * 16 + l16;
#pragma unroll
        for (int nt = 0; nt < 4; ++nt) {
            const int oc0 = n0 + nt * 16 + quad * 4;
            f32x4 bv = *reinterpret_cast<const f32x4*>(bias + oc0);
            f32x4 ovv = acc[nt] + bv;
            *reinterpret_cast<f32x4*>(out + (size_t)m * C_ + oc0) = ovv;
        }
    }
}

extern "C" void kernel_launch(void* const* d_in, const int* in_sizes, int n_in,
                              void* d_out, int out_size, void* d_ws, size_t ws_size,
                              hipStream_t stream) {
    const float* x      = (const float*)d_in[0];
    const float* w_qkv  = (const float*)d_in[1];
    const float* w_proj = (const float*)d_in[2];
    const float* b_proj = (const float*)d_in[3];
    float* out = (float*)d_out;

    const size_t qkv_elems = (size_t)B_ * H_ * N_ * D_;   // 4,194,304
    bf16* q_ws  = (bf16*)d_ws;
    bf16* k_ws  = q_ws  + qkv_elems;
    f16*  vt_ws = (f16*)(k_ws + qkv_elems);
    bf16* o_ws  = (bf16*)(vt_ws + qkv_elems);
    bf16* x_bf  = o_ws  + qkv_elems;
    bf16* wq_bf = x_bf  + (size_t)B_ * N_ * C_;
    bf16* wp_bf = wq_bf + (size_t)3 * C_ * C_;

    cast_bf16    <<<2176, 256, 0, stream>>>(x, w_qkv, w_proj, x_bf, wq_bf, wp_bf);
    qkv_fast     <<<1536, 256, 0, stream>>>(x_bf, wq_bf, q_ws, k_ws, vt_ws);
    attn         <<< 512, 512, 0, stream>>>(q_ws, k_ws, vt_ws, o_ws);
    out_proj_fast<<< 512, 256, 0, stream>>>(o_ws, wp_bf, b_proj, out);
}